// Round 13
// baseline (141.799 us; speedup 1.0000x reference)
//
#include <hip/hip_runtime.h>

typedef __bf16 bf16;
typedef __bf16 bf16x4 __attribute__((ext_vector_type(4)));
typedef __bf16 bf16x8 __attribute__((ext_vector_type(8)));
typedef float  f32x4  __attribute__((ext_vector_type(4)));

#define S_LEN 2048
#define DHEAD 64
#define BH    32
#define QB    64               // q rows per block: 4 waves x 16 rows
#define KB    64               // kv rows per tile
#define NT    (S_LEN / KB)     // 32 kv tiles

static __device__ __forceinline__ void async_cp16(const bf16* g, bf16* l) {
  __builtin_amdgcn_global_load_lds(
      (const __attribute__((address_space(1))) void*)g,
      (__attribute__((address_space(3))) void*)l, 16, 0, 0);
}

static __device__ __forceinline__ f32x4 mfma_bf16(bf16x8 a, bf16x8 b, f32x4 c) {
  return __builtin_amdgcn_mfma_f32_16x16x32_bf16(a, b, c, 0, 0, 0);
}

// ---------- pre-pass: K fp32->bf16 copy + V fp32->bf16 FRAGMENT gather ----
// Vf[bh][kt][nd][h][lane][j] = V[bh][kt*64 + 32h + 16(j>>2) + 4(lane>>4) + (j&3)]
//                               [nd*16 + (lane&15)]
// so the main kernel's vf load for (h,nd) is one contiguous 1KB b128 per wave.
__global__ __launch_bounds__(256)
void kv_prep2(const float* __restrict__ K, const float* __restrict__ V,
              bf16* __restrict__ Kb, bf16* __restrict__ Vf) {
  __shared__ bf16 t[64][72];
  const int bh = blockIdx.x >> 5;     // 0..31
  const int kt = blockIdx.x & 31;     // kv tile
  const int tid = threadIdx.x;
  const size_t tbase = ((size_t)bh * S_LEN + kt * 64) * DHEAD;

  // K: straight convert, 64x64 tile
  const float* ksrc = K + tbase;
  bf16* kdst = Kb + tbase;
#pragma unroll
  for (int it = 0; it < 2; ++it) {
    const int i = tid + it * 256;       // 0..511
    const float4 a = ((const float4*)ksrc)[2 * i];
    const float4 b = ((const float4*)ksrc)[2 * i + 1];
    bf16x8 o;
    o[0] = (bf16)a.x; o[1] = (bf16)a.y; o[2] = (bf16)a.z; o[3] = (bf16)a.w;
    o[4] = (bf16)b.x; o[5] = (bf16)b.y; o[6] = (bf16)b.z; o[7] = (bf16)b.w;
    ((bf16x8*)kdst)[i] = o;
  }

  // V: stage bf16 tile [row][d] to LDS
  const float* vsrc = V + tbase;
#pragma unroll
  for (int it = 0; it < 4; ++it) {
    const int i = tid + it * 256;       // 1024 float4 chunks
    const int r = i >> 4, c4 = (i & 15) << 2;
    const float4 v = *(const float4*)(vsrc + (size_t)r * DHEAD + c4);
    bf16x4 o;
    o[0] = (bf16)v.x; o[1] = (bf16)v.y; o[2] = (bf16)v.z; o[3] = (bf16)v.w;
    *(bf16x4*)&t[r][c4] = o;
  }
  __syncthreads();

  // gather to fragment layout (8 KB per (bh,kt))
  bf16* vdst = Vf + (size_t)bh * S_LEN * DHEAD + (size_t)kt * 4096;
  const int lane = tid & 63, nd = tid >> 6;
  const int lg = lane >> 4, l15 = lane & 15;
#pragma unroll
  for (int h = 0; h < 2; ++h) {
    bf16x8 o;
#pragma unroll
    for (int j = 0; j < 8; ++j)
      o[j] = t[32 * h + 16 * (j >> 2) + 4 * lg + (j & 3)][nd * 16 + l15];
    *(bf16x8*)(vdst + ((nd * 2 + h) * 64 + lane) * 8) = o;
  }
}

// ---------- main: flash attention; 16 q-rows/wave for 4 blocks/CU occupancy;
// P in registers (k-slot remap); V frags from L2; K staged in LDS ----
__global__ __launch_bounds__(256, 4)
void attn_fwd7(const float* __restrict__ Qg0, const bf16* __restrict__ Kb0,
               const bf16* __restrict__ Vf0, float* __restrict__ Og0) {
  __shared__ __align__(16) bf16 Kl[2][KB * DHEAD];   // 16 KB, xor-swizzled

  const int tid = threadIdx.x, wid = tid >> 6, lane = tid & 63;
  const int l15 = lane & 15, lg = lane >> 4;
  const int bid = blockIdx.x;
  const int swz = ((bid & 7) << 7) | (bid >> 3);   // XCD-contiguous (1024%8==0)
  const int bh = swz >> 5;              // 0..31
  const int qb = swz & 31;              // 0..31
  const int qbase = qb * QB + wid * 16;

  const float* Qg = Qg0 + (size_t)bh * S_LEN * DHEAD;
  const bf16* Kb = Kb0 + (size_t)bh * S_LEN * DHEAD;
  const bf16* Vf = Vf0 + (size_t)bh * S_LEN * DHEAD;
  float* Og = Og0 + (size_t)bh * S_LEN * DHEAD;

  // K staging: linear LDS dest; global source chunk inverse-swizzled (rule #21)
  const int srow = wid * 8 + (lane >> 3);           // 0..31
  const int scl = ((lane & 7) ^ (srow & 7)) << 3;   // element offset in row
  const bf16* kg0 = Kb + (size_t)srow * DHEAD + scl;

#define STAGE(b, t)                                            \
  do {                                                         \
    const bf16* kg_ = kg0 + (size_t)(t) * KB * DHEAD;          \
    async_cp16(kg_, &Kl[b][wid * 512]);                        \
    async_cp16(kg_ + 32 * DHEAD, &Kl[b][2048 + wid * 512]);    \
  } while (0)

  // ---- Q fragments: lane l15 -> q-row (B-operand col)
  const float qscale = 0.125f * 1.44269504088896341f;
  bf16x8 qfrag[2];
  {
    const float* qrow = Qg + (size_t)(qbase + l15) * DHEAD;
#pragma unroll
    for (int h = 0; h < 2; ++h) {
      const float* p = qrow + h * 32 + lg * 8;
      const float4 a = *(const float4*)(p);
      const float4 b = *(const float4*)(p + 4);
      bf16x8 f;
      f[0] = (bf16)(a.x * qscale); f[1] = (bf16)(a.y * qscale);
      f[2] = (bf16)(a.z * qscale); f[3] = (bf16)(a.w * qscale);
      f[4] = (bf16)(b.x * qscale); f[5] = (bf16)(b.y * qscale);
      f[6] = (bf16)(b.z * qscale); f[7] = (bf16)(b.w * qscale);
      qfrag[h] = f;
    }
  }

  float m_l = -__builtin_inff();
  float l_l = 0.f;
  f32x4 o_acc[4];
#pragma unroll
  for (int nd = 0; nd < 4; ++nd) o_acc[nd] = f32x4{0.f, 0.f, 0.f, 0.f};

  const int kxor = (l15 & 7) << 4;      // K read swizzle: row&7 == l15&7
  const bf16* vlane = Vf + lane * 8;    // per-lane V-frag base

  STAGE(0, 0);
  __syncthreads();

  for (int kt = 0; kt < NT; ++kt) {
    const int cur = kt & 1;
    if (kt + 1 < NT) STAGE(cur ^ 1, kt + 1);

    // ---- V fragment loads for THIS tile (L2, coalesced 1KB each);
    // issued early, consumed after softmax: ~600 cyc of latency slack
    bf16x8 vf[2][4];
    {
      const bf16* vb = vlane + (size_t)kt * 4096;
#pragma unroll
      for (int nd = 0; nd < 4; ++nd)
#pragma unroll
        for (int h = 0; h < 2; ++h)
          vf[h][nd] = *(const bf16x8*)(vb + (nd * 2 + h) * 512);
    }

    // ---- S^T = K Q^T : lane holds kv = ns*16 + lg*4 + r, q = l15
    f32x4 sacc[4] = {};
    __builtin_amdgcn_s_setprio(1);
#pragma unroll
    for (int ns = 0; ns < 4; ++ns) {
      const int krow = ns * 16 + l15;
#pragma unroll
      for (int h = 0; h < 2; ++h) {
        const int kb = krow * 128 + ((((h << 2) + lg) << 4) ^ kxor);
        const bf16x8 kf = *(const bf16x8*)((const char*)&Kl[cur][0] + kb);
        sacc[ns] = mfma_bf16(kf, qfrag[h], sacc[ns]);   // swapped operands
      }
    }
    __builtin_amdgcn_s_setprio(0);

    // ---- softmax; P packed in-register (no LDS, no fence)
    float pmax = sacc[0][0];
#pragma unroll
    for (int ns = 0; ns < 4; ++ns)
#pragma unroll
      for (int r = 0; r < 4; ++r) pmax = fmaxf(pmax, sacc[ns][r]);

    if (!__all(pmax <= m_l + 8.f)) {       // rare, wave-uniform
      pmax = fmaxf(pmax, __shfl_xor(pmax, 16));
      pmax = fmaxf(pmax, __shfl_xor(pmax, 32));
      const float mn = fmaxf(m_l, pmax);
      const float alpha = __builtin_amdgcn_exp2f(m_l - mn);  // 1st tile: 0
      m_l = mn;
      l_l *= alpha;
#pragma unroll
      for (int r = 0; r < 4; ++r) {
        const float a_r = __shfl(alpha, (lane & 48) | (((lane >> 4) & 3) * 4 + r));
        o_acc[0][r] *= a_r;
        o_acc[1][r] *= a_r;
        o_acc[2][r] *= a_r;
        o_acc[3][r] *= a_r;
      }
    }

    float rsum = 0.f;
#pragma unroll
    for (int ns = 0; ns < 4; ++ns)
#pragma unroll
      for (int r = 0; r < 4; ++r) {
        const float p = __builtin_amdgcn_exp2f(sacc[ns][r] - m_l);
        sacc[ns][r] = p;
        rsum += p;
      }
    l_l += rsum;   // per-lane partial; reduced once in epilogue

    // pack P: k-slot (h,lg,j) == kv 32h+16(j>>2)+4lg+(j&3) -> lane-local regs
    bf16x8 pa[2];
#pragma unroll
    for (int r = 0; r < 4; ++r) {
      pa[0][r]     = (bf16)sacc[0][r];
      pa[0][r + 4] = (bf16)sacc[1][r];
      pa[1][r]     = (bf16)sacc[2][r];
      pa[1][r + 4] = (bf16)sacc[3][r];
    }

    // ---- O += P V : pure register dataflow (Vf uses the same k-slot map)
    __builtin_amdgcn_s_setprio(1);
#pragma unroll
    for (int h = 0; h < 2; ++h)
#pragma unroll
      for (int nd = 0; nd < 4; ++nd)
        o_acc[nd] = mfma_bf16(pa[h], vf[h][nd], o_acc[nd]);
    __builtin_amdgcn_s_setprio(0);
    __syncthreads();  // K dbuf: next tile staged; all Kl[cur] reads done
  }

  // ---- epilogue: reduce l partials, redistribute, scale, store
  l_l += __shfl_xor(l_l, 16);
  l_l += __shfl_xor(l_l, 32);   // row-wide l for q = l15
#pragma unroll
  for (int r = 0; r < 4; ++r) {
    const float l_r = __shfl(l_l, (lane & 48) | (((lane >> 4) & 3) * 4 + r));
    const float inv = 1.0f / l_r;
    float* orow = Og + (size_t)(qbase + lg * 4 + r) * DHEAD;
#pragma unroll
    for (int nd = 0; nd < 4; ++nd)
      orow[nd * 16 + l15] = o_acc[nd][r] * inv;
  }
#undef STAGE
}

// ---------- fallback (round-1 kernel) if ws_size is too small ----------
__global__ __launch_bounds__(256, 2)
void attn_fb(const float* __restrict__ Qg0, const float* __restrict__ Kg0,
             const float* __restrict__ Vg0, float* __restrict__ Og0) {
  __shared__ __align__(16) bf16 Kl[KB][72];
  __shared__ __align__(16) bf16 Vt[DHEAD][72];
  __shared__ __align__(16) bf16 Pl[4][16][72];
  const int tid = threadIdx.x, wid = tid >> 6, lane = tid & 63;
  const int l15 = lane & 15, lg = lane >> 4;
  const int bh = blockIdx.x >> 5, qb = blockIdx.x & 31;
  const int qbase = qb * 64 + wid * 16;
  const size_t base = (size_t)bh * S_LEN * DHEAD;
  const float* Qg = Qg0 + base;
  const float* Kg = Kg0 + base;
  const float* Vg = Vg0 + base;
  float* Og = Og0 + base;
  const float qscale = 0.125f * 1.44269504088896341f;
  bf16x8 qfrag[2];
  {
    const float* qrow = Qg + (size_t)(qbase + l15) * DHEAD;
#pragma unroll
    for (int h = 0; h < 2; ++h) {
      const float* p = qrow + h * 32 + lg * 8;
      const float4 a = *(const float4*)(p);
      const float4 b = *(const float4*)(p + 4);
      bf16x8 f;
      f[0] = (bf16)(a.x * qscale); f[1] = (bf16)(a.y * qscale);
      f[2] = (bf16)(a.z * qscale); f[3] = (bf16)(a.w * qscale);
      f[4] = (bf16)(b.x * qscale); f[5] = (bf16)(b.y * qscale);
      f[6] = (bf16)(b.z * qscale); f[7] = (bf16)(b.w * qscale);
      qfrag[h] = f;
    }
  }
  float m_r[4], l_r[4];
  f32x4 o_acc[4];
#pragma unroll
  for (int r = 0; r < 4; ++r) {
    m_r[r] = -__builtin_inff();
    l_r[r] = 0.f;
    o_acc[r] = f32x4{0.f, 0.f, 0.f, 0.f};
  }
  for (int kt = 0; kt < NT; ++kt) {
    __syncthreads();
#pragma unroll
    for (int it = 0; it < 4; ++it) {
      const int i = tid + it * 256;
      const int row = i >> 4, c4 = (i & 15) << 2;
      const float4 kk = *(const float4*)(Kg + (size_t)(kt * KB + row) * DHEAD + c4);
      bf16x4 kb;
      kb[0] = (bf16)kk.x; kb[1] = (bf16)kk.y; kb[2] = (bf16)kk.z; kb[3] = (bf16)kk.w;
      *(bf16x4*)&Kl[row][c4] = kb;
      const float4 vv = *(const float4*)(Vg + (size_t)(kt * KB + row) * DHEAD + c4);
      Vt[c4 + 0][row] = (bf16)vv.x;
      Vt[c4 + 1][row] = (bf16)vv.y;
      Vt[c4 + 2][row] = (bf16)vv.z;
      Vt[c4 + 3][row] = (bf16)vv.w;
    }
    __syncthreads();
    f32x4 sacc[4] = {};
#pragma unroll
    for (int ns = 0; ns < 4; ++ns)
#pragma unroll
      for (int h = 0; h < 2; ++h) {
        const bf16x8 kf = *(const bf16x8*)&Kl[ns * 16 + l15][h * 32 + lg * 8];
        sacc[ns] = mfma_bf16(qfrag[h], kf, sacc[ns]);
      }
    float rmax[4], alpha[4], rsum[4];
#pragma unroll
    for (int r = 0; r < 4; ++r)
      rmax[r] = fmaxf(fmaxf(sacc[0][r], sacc[1][r]), fmaxf(sacc[2][r], sacc[3][r]));
#pragma unroll
    for (int off = 1; off < 16; off <<= 1)
#pragma unroll
      for (int r = 0; r < 4; ++r)
        rmax[r] = fmaxf(rmax[r], __shfl_xor(rmax[r], off));
#pragma unroll
    for (int r = 0; r < 4; ++r) {
      const float mn = fmaxf(m_r[r], rmax[r]);
      alpha[r] = exp2f(m_r[r] - mn);
      m_r[r] = mn;
      rsum[r] = 0.f;
    }
#pragma unroll
    for (int ns = 0; ns < 4; ++ns)
#pragma unroll
      for (int r = 0; r < 4; ++r) {
        const float p = exp2f(sacc[ns][r] - m_r[r]);
        sacc[ns][r] = p;
        rsum[r] += p;
      }
#pragma unroll
    for (int off = 1; off < 16; off <<= 1)
#pragma unroll
      for (int r = 0; r < 4; ++r)
        rsum[r] += __shfl_xor(rsum[r], off);
#pragma unroll
    for (int r = 0; r < 4; ++r) {
      l_r[r] = l_r[r] * alpha[r] + rsum[r];
      o_acc[0][r] *= alpha[r];
      o_acc[1][r] *= alpha[r];
      o_acc[2][r] *= alpha[r];
      o_acc[3][r] *= alpha[r];
    }
#pragma unroll
    for (int ns = 0; ns < 4; ++ns)
#pragma unroll
      for (int r = 0; r < 4; ++r)
        Pl[wid][lg * 4 + r][ns * 16 + l15] = (bf16)sacc[ns][r];
    asm volatile("s_waitcnt lgkmcnt(0)" ::: "memory");
#pragma unroll
    for (int h = 0; h < 2; ++h) {
      const bf16x8 pf = *(const bf16x8*)&Pl[wid][l15][h * 32 + lg * 8];
#pragma unroll
      for (int nd = 0; nd < 4; ++nd) {
        const bf16x8 vf = *(const bf16x8*)&Vt[nd * 16 + l15][h * 32 + lg * 8];
        o_acc[nd] = mfma_bf16(pf, vf, o_acc[nd]);
      }
    }
  }
#pragma unroll
  for (int r = 0; r < 4; ++r) {
    const float inv = 1.0f / l_r[r];
    float* orow = Og + (size_t)(qbase + lg * 4 + r) * DHEAD;
#pragma unroll
    for (int nd = 0; nd < 4; ++nd)
      orow[nd * 16 + l15] = o_acc[nd][r] * inv;
  }
}

extern "C" void kernel_launch(void* const* d_in, const int* in_sizes, int n_in,
                              void* d_out, int out_size, void* d_ws, size_t ws_size,
                              hipStream_t stream) {
  const float* Q = (const float*)d_in[0];
  const float* K = (const float*)d_in[1];
  const float* V = (const float*)d_in[2];
  float* O = (float*)d_out;

  const size_t elems = (size_t)BH * S_LEN * DHEAD;   // 4,194,304
  const size_t bf16_bytes = elems * 2;               // 8,388,608
  if (ws_size >= 2 * bf16_bytes) {
    bf16* Kb = (bf16*)d_ws;
    bf16* Vf = (bf16*)((char*)d_ws + bf16_bytes);
    hipLaunchKernelGGL(kv_prep2, dim3(BH * 32), dim3(256), 0, stream, K, V, Kb, Vf);
    hipLaunchKernelGGL(attn_fwd7, dim3(BH * (S_LEN / QB)), dim3(256), 0, stream,
                       Q, Kb, Vf, O);
  } else {
    hipLaunchKernelGGL(attn_fb, dim3(1024), dim3(256), 0, stream, Q, K, V, O);
  }
}